// Round 3
// baseline (88.574 us; speedup 1.0000x reference)
//
#include <hip/hip_runtime.h>

#define NB 8192
#define ND 128
#define NC 100
#define MARGIN_F 0.3f

#define NBLK1 1024           // 4 blocks per CU
#define WAVES_PB 4           // 256 threads
// 1024 blocks * 4 waves * 2 rows = 8192 rows

#define FXSCALE 4294967296.0   // 2^32: q32.32 fixed point for deterministic atomics

// Single compute dispatch: per-block partial -> one u64 fixed-point atomicAdd;
// last block (atomic counter) converts and writes out[0].
// acc layout in workspace (zeroed by 16B memset): acc[0] = q32.32 sum (u64),
// acc[1].lo = finished-block counter (u32).
__global__ __launch_bounds__(256) void triplet_fused_kernel(
    const float* __restrict__ inputs,   // (NB, ND) fp32
    const int*   __restrict__ targets,  // (NB,) int32
    const int*   __restrict__ ixs,      // (NB, 2) int32
    const float* __restrict__ brdf,     // (NC, NC) fp32
    unsigned long long* __restrict__ acc,
    float*       __restrict__ out)
{
    const int wave = threadIdx.x >> 6;
    const int lane = threadIdx.x & 63;
    const int sub  = lane >> 5;          // which of 2 rows in this wave
    const int sl   = lane & 31;          // slot within the row (32 lanes/row)
    const int wave_id = blockIdx.x * WAVES_PB + wave;   // 0..4095
    const int row = wave_id * 2 + sub;                  // 0..8191

    const int2 ii = ((const int2*)ixs)[row];
    const int i0 = ii.x;
    const int i1 = ii.y;

    // 32 lanes * float4 = 128 floats = full row, coalesced dwordx4.
    const float4* xr = (const float4*)(inputs + (size_t)row * ND);
    const float4* xa = (const float4*)(inputs + (size_t)i0  * ND);
    const float4* xb = (const float4*)(inputs + (size_t)i1  * ND);

    float4 r = xr[sl];
    float4 a = xa[sl];
    float4 b = xb[sl];

    // brdf chain hoisted to all lanes (same-address broadcast within each
    // 32-lane group): overlaps the row loads + butterfly instead of
    // serializing after them.
    const int tt = targets[row];
    const int t0 = targets[i0];
    const int t1 = targets[i1];
    const float md1 = brdf[tt * NC + t0];
    const float md2 = brdf[tt * NC + t1];

    float da, db, t;
    t = r.x - a.x; da  = t * t;
    t = r.y - a.y; da += t * t;
    t = r.z - a.z; da += t * t;
    t = r.w - a.w; da += t * t;

    t = r.x - b.x; db  = t * t;
    t = r.y - b.y; db += t * t;
    t = r.z - b.z; db += t * t;
    t = r.w - b.w; db += t * t;

    // 5-step butterfly confined to each 32-lane group
    #pragma unroll
    for (int off = 1; off <= 16; off <<= 1) {
        da += __shfl_xor(da, off, 64);
        db += __shfl_xor(db, off, 64);
    }

    float lacc = 0.0f;
    if (sl == 0) {   // lanes 0 and 32: finish their row
        float d0 = sqrtf(fmaxf(da, 1e-12f));
        float d1 = sqrtf(fmaxf(db, 1e-12f));
        float diff = (md1 < md2) ? (d0 - d1) : (d1 - d0);
        lacc = fmaxf(diff + MARGIN_F, 0.0f);
    }
    lacc += __shfl_xor(lacc, 32, 64);   // lanes 0+32 -> lane 0

    __shared__ float wsum[WAVES_PB];
    if (lane == 0) wsum[wave] = lacc;
    __syncthreads();

    if (threadIdx.x == 0) {
        float bsum = (wsum[0] + wsum[1]) + (wsum[2] + wsum[3]);
        // Deterministic accumulation: integer adds commute exactly.
        unsigned long long q =
            (unsigned long long)__double2ll_rn((double)bsum * FXSCALE);
        atomicAdd(&acc[0], q);
        __threadfence();                             // publish sum before count
        unsigned int old =
            atomicAdd((unsigned int*)&acc[1], 1u);
        if (old == NBLK1 - 1) {                      // last block to finish
            __threadfence();                         // acquire all sum-adds
            unsigned long long total = atomicAdd(&acc[0], 0ULL); // coherent read
            out[0] = (float)((double)total * (1.0 / FXSCALE) / (double)NB);
        }
    }
}

extern "C" void kernel_launch(void* const* d_in, const int* in_sizes, int n_in,
                              void* d_out, int out_size, void* d_ws, size_t ws_size,
                              hipStream_t stream) {
    const float* inputs  = (const float*)d_in[0];
    const int*   targets = (const int*)d_in[1];
    const int*   ixs     = (const int*)d_in[2];
    const float* brdf    = (const float*)d_in[3];
    float* out = (float*)d_out;
    unsigned long long* acc = (unsigned long long*)d_ws;

    hipMemsetAsync(acc, 0, 16, stream);   // zero {sum, counter} — graph-capturable
    triplet_fused_kernel<<<NBLK1, 256, 0, stream>>>(inputs, targets, ixs, brdf, acc, out);
}